// Round 3
// baseline (1048.831 us; speedup 1.0000x reference)
//
#include <hip/hip_runtime.h>
#include <hip/hip_bf16.h>
#include <math.h>

// Problem constants
#define BB 2
#define TT 512
#define DM 1024
#define DI 2048
#define DCONV 4
#define NH 32
#define NS 32
#define DH 64
#define PROJW 4160   // 2*DI + NH*2
#define BT (BB*TT)   // 1024

__device__ __forceinline__ float sigmoidf_(float x) { return 1.0f / (1.0f + expf(-x)); }
__device__ __forceinline__ float siluf_(float x) { return x * sigmoidf_(x); }

// ---------------------------------------------------------------------------
// fp32 NT-GEMM v2: C[m,n] = sum_k A[m,k]*B[n,k]
// BM=128, BN=64, BK=8, TM=8, TN=4, 256 threads (16x16).
// ---------------------------------------------------------------------------
__global__ __launch_bounds__(256) void gemm_nt_v2(const float* __restrict__ A,
                                                  const float* __restrict__ B,
                                                  float* __restrict__ C,
                                                  int M, int N, int K) {
    constexpr int BM = 128, BN = 64, BK = 8, TM = 8, TN = 4;
    __shared__ float As[BK][BM];
    __shared__ float Bs[BK][BN];
    const int t = threadIdx.x;
    const int m0 = blockIdx.y * BM;
    const int n0 = blockIdx.x * BN;
    const int tx = t & 15;        // n
    const int ty = t >> 4;        // m

    const int arow = t >> 1, akc = (t & 1) << 2;   // A stage: 128 rows x 2 k-halves
    const int brow = t >> 1, bkc = (t & 1) << 2;   // B stage: threads < 128

    float acc[TM][TN];
#pragma unroll
    for (int i = 0; i < TM; i++)
#pragma unroll
        for (int j = 0; j < TN; j++) acc[i][j] = 0.0f;

    const float* Ab = A + (size_t)(m0 + arow) * K + akc;
    const float* Bb = B + (size_t)(n0 + brow) * K + bkc;

    for (int k0 = 0; k0 < K; k0 += BK) {
        float4 av = *(const float4*)(Ab + k0);
        As[akc + 0][arow] = av.x; As[akc + 1][arow] = av.y;
        As[akc + 2][arow] = av.z; As[akc + 3][arow] = av.w;
        if (t < 128) {
            float4 bv = *(const float4*)(Bb + k0);
            Bs[bkc + 0][brow] = bv.x; Bs[bkc + 1][brow] = bv.y;
            Bs[bkc + 2][brow] = bv.z; Bs[bkc + 3][brow] = bv.w;
        }
        __syncthreads();
#pragma unroll
        for (int k = 0; k < BK; k++) {
            float4 a0 = *(const float4*)&As[k][ty * TM];
            float4 a1 = *(const float4*)&As[k][ty * TM + 4];
            float4 b0 = *(const float4*)&Bs[k][tx * TN];
            float a[8] = {a0.x, a0.y, a0.z, a0.w, a1.x, a1.y, a1.z, a1.w};
            float b[4] = {b0.x, b0.y, b0.z, b0.w};
#pragma unroll
            for (int i = 0; i < TM; i++)
#pragma unroll
                for (int j = 0; j < TN; j++)
                    acc[i][j] = fmaf(a[i], b[j], acc[i][j]);
        }
        __syncthreads();
    }
#pragma unroll
    for (int i = 0; i < TM; i++) {
        float4 v = {acc[i][0], acc[i][1], acc[i][2], acc[i][3]};
        *(float4*)&C[(size_t)(m0 + ty * TM + i) * N + n0 + tx * TN] = v;
    }
}

// depthwise causal conv (K=4) over value_raw slice of proj, then SiLU
__global__ __launch_bounds__(256) void conv_silu_kernel(const float* __restrict__ proj,
                                                        const float* __restrict__ dw_w,
                                                        const float* __restrict__ dw_b,
                                                        float* __restrict__ value) {
    int idx = blockIdx.x * 256 + threadIdx.x;     // < BT*DI
    int di = idx & (DI - 1);
    int bt = idx >> 11;
    int t = bt & (TT - 1);
    const float* vr = proj + (size_t)bt * PROJW + DI + di;  // value_raw[bt][di]
    float4 w = *(const float4*)&dw_w[di * 4];
    float acc = dw_b[di];
    if (t >= 3) acc = fmaf(vr[-3 * PROJW], w.x, acc);
    if (t >= 2) acc = fmaf(vr[-2 * PROJW], w.y, acc);
    if (t >= 1) acc = fmaf(vr[-1 * PROJW], w.z, acc);
    acc = fmaf(vr[0], w.w, acc);
    value[idx] = siluf_(acc);
}

// per (bt,h,n): dt (softplus+clip), S = 1/(1 + dt*kd + dt^2*A)
__global__ __launch_bounds__(256) void dtkd_S_kernel(const float* __restrict__ proj,
                                                     const float* __restrict__ dt_bias,
                                                     const float* __restrict__ A_log,
                                                     float* __restrict__ dt_a,
                                                     float* __restrict__ S_a) {
    int idx = blockIdx.x * 256 + threadIdx.x;     // < BT*NH*NS
    int n = idx & (NS - 1);
    int h = (idx >> 5) & (NH - 1);
    int bt = idx >> 10;
    const float* prow = proj + (size_t)bt * PROJW + 2 * DI;
    float p0 = prow[2 * h], p1 = prow[2 * h + 1];
    float xdt = p0 + dt_bias[h];
    float sp = fmaxf(xdt, 0.0f) + log1pf(expf(-fabsf(xdt)));
    float dt = fminf(fmaxf(sp, 1e-4f), 0.1f);
    float kd = 0.5f * sigmoidf_(p1);
    float A = expf(A_log[h * NS + n]);
    float S = 1.0f / (1.0f + dt * kd + dt * dt * A);
    S_a[idx] = S;
    if (n == 0) dt_a[bt * NH + h] = dt;
}

// L2-normalize bc over groups of 32 (intra-32-lane shfl reduce)
__global__ __launch_bounds__(256) void normalize_kernel(float* __restrict__ bc) {
    int idx = blockIdx.x * 256 + threadIdx.x;     // < BT*4096
    float v = bc[idx];
    float ss = v * v;
    ss += __shfl_xor(ss, 1);
    ss += __shfl_xor(ss, 2);
    ss += __shfl_xor(ss, 4);
    ss += __shfl_xor(ss, 8);
    ss += __shfl_xor(ss, 16);
    bc[idx] = v / (sqrtf(ss) + 1e-8f);
}

// ---------------------------------------------------------------------------
// sequential scan with distance-2 software-pipelined prefetch.
// One block per (b,h); 256 threads = 4 waves; wave w owns d in [16w,16w+16);
// lane group ng = l>>4 owns n in [8*ng, 8*ng+8).
// ---------------------------------------------------------------------------
struct SRegs {
    float bz[8], bx[8], cz[8], cx[8], S[8];
    float u, dt;
};

__device__ __forceinline__ void scan_load(SRegs& r,
                                          const float* __restrict__ bcp,
                                          const float* __restrict__ Sp,
                                          const float* __restrict__ vp,
                                          const float* __restrict__ dtp,
                                          int t) {
    const float* b = bcp + (size_t)t * 4096;
    *(float4*)&r.bz[0] = *(const float4*)(b + 0);
    *(float4*)&r.bz[4] = *(const float4*)(b + 4);
    *(float4*)&r.bx[0] = *(const float4*)(b + 32);
    *(float4*)&r.bx[4] = *(const float4*)(b + 36);
    *(float4*)&r.cz[0] = *(const float4*)(b + 64);
    *(float4*)&r.cz[4] = *(const float4*)(b + 68);
    *(float4*)&r.cx[0] = *(const float4*)(b + 96);
    *(float4*)&r.cx[4] = *(const float4*)(b + 100);
    const float* s = Sp + (size_t)t * (NH * NS);
    *(float4*)&r.S[0] = *(const float4*)(s + 0);
    *(float4*)&r.S[4] = *(const float4*)(s + 4);
    r.u = vp[(size_t)t * DI];
    r.dt = dtp[(size_t)t * NH];
}

__global__ __launch_bounds__(256, 1) void scan_kernel(const float* __restrict__ value,
                                                      const float* __restrict__ bc,
                                                      const float* __restrict__ dt_a,
                                                      const float* __restrict__ S_a,
                                                      const float* __restrict__ A_log,
                                                      float* __restrict__ yout) {
    const int bh = blockIdx.x;
    const int b = bh >> 5, h = bh & (NH - 1);
    const int tid = threadIdx.x;
    const int w = tid >> 6, l = tid & 63;
    const int d = w * 16 + (l & 15);
    const int ng = l >> 4;
    const int n0 = ng * 8;

    float a[8];
#pragma unroll
    for (int j = 0; j < 8; j++) a[j] = expf(A_log[h * NS + n0 + j]);

    float z[8], s[8];
#pragma unroll
    for (int j = 0; j < 8; j++) { z[j] = 0.0f; s[j] = 0.0f; }

    const float* vptr = value + (size_t)b * TT * DI + h * DH + d;
    const float* bcp  = bc + (size_t)b * TT * 4096 + h * 128 + n0;
    const float* dtp  = dt_a + (size_t)b * TT * NH + h;
    const float* Sp   = S_a + (size_t)b * TT * (NH * NS) + h * NS + n0;
    float* yp = yout + (size_t)b * TT * DI + h * DH + d;

    SRegs rA, rB, rC, rD;
    scan_load(rA, bcp, Sp, vptr, dtp, 0);
    scan_load(rB, bcp, Sp, vptr, dtp, 1);

    for (int t = 0; t < TT; t += 2) {
        int t2 = t + 2 < TT ? t + 2 : TT - 1;
        int t3 = t + 3 < TT ? t + 3 : TT - 1;
        scan_load(rC, bcp, Sp, vptr, dtp, t2);

        // ---- step t with rA ----
        {
            float dt = rA.dt;
            float dtu = dt * rA.u;
            float y0 = 0.0f, y1 = 0.0f;
#pragma unroll
            for (int j = 0; j < 8; j++) {
                float dtA = dt * a[j];
                float t1v = fmaf(-dtA, s[j], z[j]);
                float t2v = fmaf(dtu, rA.bz[j], t1v);
                float zn = rA.S[j] * t2v;
                z[j] = zn;
                float sn = fmaf(dt, zn, fmaf(dtu, rA.bx[j], s[j]));
                s[j] = sn;
                if (j & 1) { y1 = fmaf(rA.cz[j], zn, y1); y1 = fmaf(rA.cx[j], sn, y1); }
                else       { y0 = fmaf(rA.cz[j], zn, y0); y0 = fmaf(rA.cx[j], sn, y0); }
            }
            float y = y0 + y1;
            y += __shfl_xor(y, 16);
            y += __shfl_xor(y, 32);
            if (ng == 0) yp[(size_t)t * DI] = y;
        }

        scan_load(rD, bcp, Sp, vptr, dtp, t3);

        // ---- step t+1 with rB ----
        {
            float dt = rB.dt;
            float dtu = dt * rB.u;
            float y0 = 0.0f, y1 = 0.0f;
#pragma unroll
            for (int j = 0; j < 8; j++) {
                float dtA = dt * a[j];
                float t1v = fmaf(-dtA, s[j], z[j]);
                float t2v = fmaf(dtu, rB.bz[j], t1v);
                float zn = rB.S[j] * t2v;
                z[j] = zn;
                float sn = fmaf(dt, zn, fmaf(dtu, rB.bx[j], s[j]));
                s[j] = sn;
                if (j & 1) { y1 = fmaf(rB.cz[j], zn, y1); y1 = fmaf(rB.cx[j], sn, y1); }
                else       { y0 = fmaf(rB.cz[j], zn, y0); y0 = fmaf(rB.cx[j], sn, y0); }
            }
            float y = y0 + y1;
            y += __shfl_xor(y, 16);
            y += __shfl_xor(y, 32);
            if (ng == 0) yp[(size_t)(t + 1) * DI] = y;
        }

        rA = rC;
        rB = rD;
    }
}

// y = (y + skip*value) * silu(gate)   (in place on yscan)
__global__ __launch_bounds__(256) void fuse_kernel(const float* __restrict__ proj,
                                                   const float* __restrict__ value,
                                                   const float* __restrict__ skip,
                                                   float* __restrict__ ysc) {
    int idx = blockIdx.x * 256 + threadIdx.x;     // < BT*DI
    int di = idx & (DI - 1);
    int bt = idx >> 11;
    float g = proj[(size_t)bt * PROJW + di];
    float yv = ysc[idx];
    float v = value[idx];
    ysc[idx] = fmaf(skip[di], v, yv) * siluf_(g);
}

extern "C" void kernel_launch(void* const* d_in, const int* in_sizes, int n_in,
                              void* d_out, int out_size, void* d_ws, size_t ws_size,
                              hipStream_t stream) {
    const float* x       = (const float*)d_in[0];
    const float* W_in    = (const float*)d_in[1];
    const float* dw_w    = (const float*)d_in[2];
    const float* dw_b    = (const float*)d_in[3];
    const float* W_bc    = (const float*)d_in[4];
    const float* W_out   = (const float*)d_in[5];
    const float* skip    = (const float*)d_in[6];
    const float* A_log   = (const float*)d_in[7];
    const float* dt_bias = (const float*)d_in[8];
    float* out = (float*)d_out;

    float* ws    = (float*)d_ws;
    float* proj  = ws;                                // BT*PROJW = 4,259,840
    float* value = proj  + (size_t)BT * PROJW;        // BT*DI    = 2,097,152
    float* dt_a  = value + (size_t)BT * DI;           // BT*NH    = 32,768
    float* S_a   = dt_a  + (size_t)BT * NH;           // BT*NH*NS = 1,048,576
    float* bcw   = S_a   + (size_t)BT * NH * NS;      // BT*4096  = 4,194,304
    float* ysc   = bcw   + (size_t)BT * 4096;         // BT*DI    = 2,097,152

    dim3 blk(256);

    // 1) proj = x @ W_in^T : M=1024, N=4160, K=1024   (4160/64 = 65)
    gemm_nt_v2<<<dim3(PROJW / 64, BT / 128), blk, 0, stream>>>(x, W_in, proj, BT, PROJW, DM);

    // 2) conv + silu -> value
    conv_silu_kernel<<<dim3(BT * DI / 256), blk, 0, stream>>>(proj, dw_w, dw_b, value);

    // 3) dt + S precompute
    dtkd_S_kernel<<<dim3(BT * NH * NS / 256), blk, 0, stream>>>(proj, dt_bias, A_log, dt_a, S_a);

    // 4) bc = value @ W_bc^T : M=1024, N=4096, K=2048
    gemm_nt_v2<<<dim3(4096 / 64, BT / 128), blk, 0, stream>>>(value, W_bc, bcw, BT, 4096, DI);

    // 5) normalize bc groups of 32
    normalize_kernel<<<dim3(BT * 4096 / 256), blk, 0, stream>>>(bcw);

    // 6) sequential scan (software-pipelined, distance-2 prefetch)
    scan_kernel<<<dim3(BB * NH), blk, 0, stream>>>(value, bcw, dt_a, S_a, A_log, ysc);

    // 7) fuse skip/gate
    fuse_kernel<<<dim3(BT * DI / 256), blk, 0, stream>>>(proj, value, skip, ysc);

    // 8) out = ysc @ W_out^T : M=1024, N=1024, K=2048
    gemm_nt_v2<<<dim3(DM / 64, BT / 128), blk, 0, stream>>>(ysc, W_out, out, BT, DM, DI);
}

// Round 7
// 579.775 us; speedup vs baseline: 1.8090x; 1.8090x over previous
//
#include <hip/hip_runtime.h>
#include <hip/hip_bf16.h>
#include <math.h>

// Problem constants
#define BB 2
#define TT 512
#define DM 1024
#define DI 2048
#define DCONV 4
#define NH 32
#define NS 32
#define DH 64
#define PROJW 4160   // 2*DI + NH*2
#define BT (BB*TT)   // 1024

typedef unsigned short u16;
typedef short bf16x8v __attribute__((ext_vector_type(8)));
typedef float f32x4 __attribute__((ext_vector_type(4)));
typedef u16 u16x4 __attribute__((ext_vector_type(4)));

__device__ __forceinline__ float sigmoidf_(float x) { return 1.0f / (1.0f + expf(-x)); }
__device__ __forceinline__ float siluf_(float x) { return x * sigmoidf_(x); }

// RNE split: x ~= h + s (both bf16), returned by value
struct HS { u16 h, s; };
__device__ __forceinline__ HS split1(float x) {
    HS r;
    unsigned u = __float_as_uint(x);
    unsigned rr = u + 0x7fffu + ((u >> 16) & 1u);
    r.h = (u16)(rr >> 16);
    float hf = __uint_as_float(((unsigned)r.h) << 16);
    float res = x - hf;
    unsigned u2 = __float_as_uint(res);
    unsigned r2 = u2 + 0x7fffu + ((u2 >> 16) & 1u);
    r.s = (u16)(r2 >> 16);
    return r;
}

__device__ __forceinline__ void async_copy16(const void* g, void* l) {
    __builtin_amdgcn_global_load_lds(
        (__attribute__((address_space(1))) void*)const_cast<void*>(g),
        (__attribute__((address_space(3))) void*)l,
        16, 0, 0);
}

// elementwise fp32 -> (hi, lo) bf16 arrays, 4 elems/thread
__global__ __launch_bounds__(256) void split_kernel(const float* __restrict__ in,
                                                    u16* __restrict__ hi,
                                                    u16* __restrict__ lo,
                                                    int n4) {
    int i = blockIdx.x * 256 + threadIdx.x;
    if (i >= n4) return;
    float4 v = ((const float4*)in)[i];
    HS a = split1(v.x), b = split1(v.y), c = split1(v.z), d = split1(v.w);
    u16x4 h, s;
    h.x = a.h; h.y = b.h; h.z = c.h; h.w = d.h;
    s.x = a.s; s.y = b.s; s.z = c.s; s.w = d.s;
    ((u16x4*)hi)[i] = h;
    ((u16x4*)lo)[i] = s;
}

// ---------------------------------------------------------------------------
// bf16x3 MFMA NT-GEMM: C[m,n] = sum_k A[m,k]*B[n,k], A=Ah+Al, B=Bh+Bl.
// 256 threads = 4 waves (2x2). Per wave: MF x NF 16x16 frags.
// LDS tiles [rows][32] bf16, staged via global_load_lds (16B/lane).
// ---------------------------------------------------------------------------
template<int BM, int BN, bool GUARD>
__global__ __launch_bounds__(256) void gemm_bf16x3(const u16* __restrict__ Ah,
                                                   const u16* __restrict__ Al,
                                                   const u16* __restrict__ Bh,
                                                   const u16* __restrict__ Bl,
                                                   float* __restrict__ C,
                                                   int M, int N, int K) {
    constexpr int MF = BM / 32;
    constexpr int NF = BN / 32;
    constexpr int ASEG = BM / 16, BSEG = BN / 16;
    constexpr int NSEG = 2 * ASEG + 2 * BSEG;
    constexpr int SEGW = NSEG / 4;

    __shared__ u16 lds[(2 * BM + 2 * BN) * 32];
    u16* Ah_s = lds;
    u16* Al_s = lds + BM * 32;
    u16* Bh_s = lds + 2 * BM * 32;
    u16* Bl_s = lds + (2 * BM + BN) * 32;

    const int tid = threadIdx.x;
    const int l = tid & 63;
    const int w = tid >> 6;
    const int wm = w >> 1, wn = w & 1;

    const int m0 = blockIdx.y * BM;
    const int n0 = blockIdx.x * BN;

    // staging segment setup: seg -> (global base, lds base)
    const u16* segg[SEGW];
    u16* segl[SEGW];
#pragma unroll
    for (int si = 0; si < SEGW; ++si) {
        int seg = w + si * 4;
        const u16* gmat;
        u16* lmat;
        int r0, rbase;
        if (seg < ASEG)                { gmat = Ah; lmat = Ah_s; r0 = seg * 16;                  rbase = m0; }
        else if (seg < 2 * ASEG)       { gmat = Al; lmat = Al_s; r0 = (seg - ASEG) * 16;         rbase = m0; }
        else if (seg < 2 * ASEG + BSEG){ gmat = Bh; lmat = Bh_s; r0 = (seg - 2 * ASEG) * 16;     rbase = n0; }
        else                           { gmat = Bl; lmat = Bl_s; r0 = (seg - 2 * ASEG - BSEG) * 16; rbase = n0; }
        segg[si] = gmat + (size_t)(rbase + r0 + (l >> 2)) * K + (l & 3) * 8;
        segl[si] = lmat + r0 * 32;
    }

    f32x4 acc[MF][NF];
#pragma unroll
    for (int i = 0; i < MF; ++i)
#pragma unroll
        for (int j = 0; j < NF; ++j) {
            f32x4 z = {0.0f, 0.0f, 0.0f, 0.0f};
            acc[i][j] = z;
        }

    const int lrow = l & 15;
    const int lko = (l >> 4) * 8;

    for (int k0 = 0; k0 < K; k0 += 32) {
#pragma unroll
        for (int si = 0; si < SEGW; ++si)
            async_copy16(segg[si] + k0, segl[si]);
        __syncthreads();

        bf16x8v af[MF][2], bfv[NF][2];
#pragma unroll
        for (int i = 0; i < MF; ++i) {
            int r = wm * (MF * 16) + i * 16 + lrow;
            af[i][0] = *(const bf16x8v*)&Ah_s[r * 32 + lko];
            af[i][1] = *(const bf16x8v*)&Al_s[r * 32 + lko];
        }
#pragma unroll
        for (int j = 0; j < NF; ++j) {
            int r = wn * (NF * 16) + j * 16 + lrow;
            bfv[j][0] = *(const bf16x8v*)&Bh_s[r * 32 + lko];
            bfv[j][1] = *(const bf16x8v*)&Bl_s[r * 32 + lko];
        }
#pragma unroll
        for (int i = 0; i < MF; ++i)
#pragma unroll
            for (int j = 0; j < NF; ++j) {
                acc[i][j] = __builtin_amdgcn_mfma_f32_16x16x32_bf16(af[i][0], bfv[j][0], acc[i][j], 0, 0, 0);
                acc[i][j] = __builtin_amdgcn_mfma_f32_16x16x32_bf16(af[i][0], bfv[j][1], acc[i][j], 0, 0, 0);
                acc[i][j] = __builtin_amdgcn_mfma_f32_16x16x32_bf16(af[i][1], bfv[j][0], acc[i][j], 0, 0, 0);
            }
        __syncthreads();
    }

    // store: D row=(l>>4)*4+reg, col=l&15  [m89 layout]
#pragma unroll
    for (int i = 0; i < MF; ++i) {
        int mrow = m0 + wm * (MF * 16) + i * 16 + (l >> 4) * 4;
#pragma unroll
        for (int j = 0; j < NF; ++j) {
            int ncol = n0 + wn * (NF * 16) + j * 16 + lrow;
            if (!GUARD || ncol < N) {
#pragma unroll
                for (int r = 0; r < 4; ++r)
                    C[(size_t)(mrow + r) * N + ncol] = acc[i][j][r];
            }
        }
    }
}

// depthwise causal conv (K=4) + SiLU, 4 channels/thread; also writes bf16 split
__global__ __launch_bounds__(256) void conv_silu_kernel(const float* __restrict__ proj,
                                                        const float* __restrict__ dw_w,
                                                        const float* __restrict__ dw_b,
                                                        float* __restrict__ value,
                                                        u16* __restrict__ vh,
                                                        u16* __restrict__ vl) {
    int i = blockIdx.x * 256 + threadIdx.x;      // < BT*DI/4
    int dq = i & (DI / 4 - 1);
    int bt = i >> 9;
    int t = bt & (TT - 1);
    int di = dq * 4;
    const float* vr = proj + (size_t)bt * PROJW + DI + di;
    float4 zz = {0, 0, 0, 0};
    float4 x0 = (t >= 3) ? *(const float4*)(vr - 3 * PROJW) : zz;
    float4 x1 = (t >= 2) ? *(const float4*)(vr - 2 * PROJW) : zz;
    float4 x2 = (t >= 1) ? *(const float4*)(vr - 1 * PROJW) : zz;
    float4 x3 = *(const float4*)vr;
    float4 w0 = *(const float4*)&dw_w[(di + 0) * 4];
    float4 w1 = *(const float4*)&dw_w[(di + 1) * 4];
    float4 w2 = *(const float4*)&dw_w[(di + 2) * 4];
    float4 w3 = *(const float4*)&dw_w[(di + 3) * 4];
    float4 bb = *(const float4*)&dw_b[di];
    float4 v;
    v.x = siluf_(bb.x + x0.x * w0.x + x1.x * w0.y + x2.x * w0.z + x3.x * w0.w);
    v.y = siluf_(bb.y + x0.y * w1.x + x1.y * w1.y + x2.y * w1.z + x3.y * w1.w);
    v.z = siluf_(bb.z + x0.z * w2.x + x1.z * w2.y + x2.z * w2.z + x3.z * w2.w);
    v.w = siluf_(bb.w + x0.w * w3.x + x1.w * w3.y + x2.w * w3.z + x3.w * w3.w);
    ((float4*)value)[i] = v;
    HS a = split1(v.x), b = split1(v.y), c = split1(v.z), d = split1(v.w);
    u16x4 h, s;
    h.x = a.h; h.y = b.h; h.z = c.h; h.w = d.h;
    s.x = a.s; s.y = b.s; s.z = c.s; s.w = d.s;
    ((u16x4*)vh)[i] = h;
    ((u16x4*)vl)[i] = s;
}

// per (bt,h,n): dt (softplus+clip), S = 1/(1 + dt*kd + dt^2*A)
__global__ __launch_bounds__(256) void dtkd_S_kernel(const float* __restrict__ proj,
                                                     const float* __restrict__ dt_bias,
                                                     const float* __restrict__ A_log,
                                                     float* __restrict__ dt_a,
                                                     float* __restrict__ S_a) {
    int idx = blockIdx.x * 256 + threadIdx.x;     // < BT*NH*NS
    int n = idx & (NS - 1);
    int h = (idx >> 5) & (NH - 1);
    int bt = idx >> 10;
    const float* prow = proj + (size_t)bt * PROJW + 2 * DI;
    float p0 = prow[2 * h], p1 = prow[2 * h + 1];
    float xdt = p0 + dt_bias[h];
    float sp = fmaxf(xdt, 0.0f) + log1pf(expf(-fabsf(xdt)));
    float dt = fminf(fmaxf(sp, 1e-4f), 0.1f);
    float kd = 0.5f * sigmoidf_(p1);
    float A = expf(A_log[h * NS + n]);
    float S = 1.0f / (1.0f + dt * kd + dt * dt * A);
    S_a[idx] = S;
    if (n == 0) dt_a[bt * NH + h] = dt;
}

// L2-normalize bc over groups of 32
__global__ __launch_bounds__(256) void normalize_kernel(float* __restrict__ bc) {
    int idx = blockIdx.x * 256 + threadIdx.x;     // < BT*4096
    float v = bc[idx];
    float ss = v * v;
    ss += __shfl_xor(ss, 1);
    ss += __shfl_xor(ss, 2);
    ss += __shfl_xor(ss, 4);
    ss += __shfl_xor(ss, 8);
    ss += __shfl_xor(ss, 16);
    bc[idx] = v / (sqrtf(ss) + 1e-8f);
}

// ---------------------------------------------------------------------------
// sequential scan with distance-2 software-pipelined prefetch
// ---------------------------------------------------------------------------
struct SRegs {
    float bz[8], bx[8], cz[8], cx[8], S[8];
    float u, dt;
};

__device__ __forceinline__ void scan_load(SRegs& r,
                                          const float* __restrict__ bcp,
                                          const float* __restrict__ Sp,
                                          const float* __restrict__ vp,
                                          const float* __restrict__ dtp,
                                          int t) {
    const float* b = bcp + (size_t)t * 4096;
    *(float4*)&r.bz[0] = *(const float4*)(b + 0);
    *(float4*)&r.bz[4] = *(const float4*)(b + 4);
    *(float4*)&r.bx[0] = *(const float4*)(b + 32);
    *(float4*)&r.bx[4] = *(const float4*)(b + 36);
    *(float4*)&r.cz[0] = *(const float4*)(b + 64);
    *(float4*)&r.cz[4] = *(const float4*)(b + 68);
    *(float4*)&r.cx[0] = *(const float4*)(b + 96);
    *(float4*)&r.cx[4] = *(const float4*)(b + 100);
    const float* s = Sp + (size_t)t * (NH * NS);
    *(float4*)&r.S[0] = *(const float4*)(s + 0);
    *(float4*)&r.S[4] = *(const float4*)(s + 4);
    r.u = vp[(size_t)t * DI];
    r.dt = dtp[(size_t)t * NH];
}

__global__ __launch_bounds__(256, 1) void scan_kernel(const float* __restrict__ value,
                                                      const float* __restrict__ bc,
                                                      const float* __restrict__ dt_a,
                                                      const float* __restrict__ S_a,
                                                      const float* __restrict__ A_log,
                                                      float* __restrict__ yout) {
    const int bh = blockIdx.x;
    const int b = bh >> 5, h = bh & (NH - 1);
    const int tid = threadIdx.x;
    const int w = tid >> 6, l = tid & 63;
    const int d = w * 16 + (l & 15);
    const int ng = l >> 4;
    const int n0 = ng * 8;

    float a[8];
#pragma unroll
    for (int j = 0; j < 8; j++) a[j] = expf(A_log[h * NS + n0 + j]);

    float z[8], s[8];
#pragma unroll
    for (int j = 0; j < 8; j++) { z[j] = 0.0f; s[j] = 0.0f; }

    const float* vptr = value + (size_t)b * TT * DI + h * DH + d;
    const float* bcp  = bc + (size_t)b * TT * 4096 + h * 128 + n0;
    const float* dtp  = dt_a + (size_t)b * TT * NH + h;
    const float* Sp   = S_a + (size_t)b * TT * (NH * NS) + h * NS + n0;
    float* yp = yout + (size_t)b * TT * DI + h * DH + d;

    SRegs rA, rB, rC, rD;
    scan_load(rA, bcp, Sp, vptr, dtp, 0);
    scan_load(rB, bcp, Sp, vptr, dtp, 1);

    for (int t = 0; t < TT; t += 2) {
        int t2 = t + 2 < TT ? t + 2 : TT - 1;
        int t3 = t + 3 < TT ? t + 3 : TT - 1;
        scan_load(rC, bcp, Sp, vptr, dtp, t2);

        {
            float dt = rA.dt;
            float dtu = dt * rA.u;
            float y0 = 0.0f, y1 = 0.0f;
#pragma unroll
            for (int j = 0; j < 8; j++) {
                float dtA = dt * a[j];
                float t1v = fmaf(-dtA, s[j], z[j]);
                float t2v = fmaf(dtu, rA.bz[j], t1v);
                float zn = rA.S[j] * t2v;
                z[j] = zn;
                float sn = fmaf(dt, zn, fmaf(dtu, rA.bx[j], s[j]));
                s[j] = sn;
                if (j & 1) { y1 = fmaf(rA.cz[j], zn, y1); y1 = fmaf(rA.cx[j], sn, y1); }
                else       { y0 = fmaf(rA.cz[j], zn, y0); y0 = fmaf(rA.cx[j], sn, y0); }
            }
            float y = y0 + y1;
            y += __shfl_xor(y, 16);
            y += __shfl_xor(y, 32);
            if (ng == 0) yp[(size_t)t * DI] = y;
        }

        scan_load(rD, bcp, Sp, vptr, dtp, t3);

        {
            float dt = rB.dt;
            float dtu = dt * rB.u;
            float y0 = 0.0f, y1 = 0.0f;
#pragma unroll
            for (int j = 0; j < 8; j++) {
                float dtA = dt * a[j];
                float t1v = fmaf(-dtA, s[j], z[j]);
                float t2v = fmaf(dtu, rB.bz[j], t1v);
                float zn = rB.S[j] * t2v;
                z[j] = zn;
                float sn = fmaf(dt, zn, fmaf(dtu, rB.bx[j], s[j]));
                s[j] = sn;
                if (j & 1) { y1 = fmaf(rB.cz[j], zn, y1); y1 = fmaf(rB.cx[j], sn, y1); }
                else       { y0 = fmaf(rB.cz[j], zn, y0); y0 = fmaf(rB.cx[j], sn, y0); }
            }
            float y = y0 + y1;
            y += __shfl_xor(y, 16);
            y += __shfl_xor(y, 32);
            if (ng == 0) yp[(size_t)(t + 1) * DI] = y;
        }

        rA = rC;
        rB = rD;
    }
}

// y = (y + skip*value) * silu(gate); writes bf16 split only (consumed by GEMM3)
__global__ __launch_bounds__(256) void fuse_kernel(const float* __restrict__ proj,
                                                   const float* __restrict__ value,
                                                   const float* __restrict__ skip,
                                                   const float* __restrict__ ysc,
                                                   u16* __restrict__ yh,
                                                   u16* __restrict__ yl) {
    int i = blockIdx.x * 256 + threadIdx.x;      // < BT*DI/4
    int dq = i & (DI / 4 - 1);
    int bt = i >> 9;
    int di = dq * 4;
    float4 g = *(const float4*)&proj[(size_t)bt * PROJW + di];
    float4 yv = ((const float4*)ysc)[i];
    float4 v = ((const float4*)value)[i];
    float4 sk = *(const float4*)&skip[di];
    float4 r;
    r.x = fmaf(sk.x, v.x, yv.x) * siluf_(g.x);
    r.y = fmaf(sk.y, v.y, yv.y) * siluf_(g.y);
    r.z = fmaf(sk.z, v.z, yv.z) * siluf_(g.z);
    r.w = fmaf(sk.w, v.w, yv.w) * siluf_(g.w);
    HS a = split1(r.x), b = split1(r.y), c = split1(r.z), d = split1(r.w);
    u16x4 h, s;
    h.x = a.h; h.y = b.h; h.z = c.h; h.w = d.h;
    s.x = a.s; s.y = b.s; s.z = c.s; s.w = d.s;
    ((u16x4*)yh)[i] = h;
    ((u16x4*)yl)[i] = s;
}

extern "C" void kernel_launch(void* const* d_in, const int* in_sizes, int n_in,
                              void* d_out, int out_size, void* d_ws, size_t ws_size,
                              hipStream_t stream) {
    const float* x       = (const float*)d_in[0];
    const float* W_in    = (const float*)d_in[1];
    const float* dw_w    = (const float*)d_in[2];
    const float* dw_b    = (const float*)d_in[3];
    const float* W_bc    = (const float*)d_in[4];
    const float* W_out   = (const float*)d_in[5];
    const float* skip    = (const float*)d_in[6];
    const float* A_log   = (const float*)d_in[7];
    const float* dt_bias = (const float*)d_in[8];
    float* out = (float*)d_out;

    float* ws    = (float*)d_ws;
    float* proj  = ws;                                // 4,259,840 f
    float* value = proj  + (size_t)BT * PROJW;        // 2,097,152
    float* dt_a  = value + (size_t)BT * DI;           // 32,768
    float* S_a   = dt_a  + (size_t)BT * NH;           // 1,048,576
    float* bcw   = S_a   + (size_t)BT * NH * NS;      // 4,194,304
    float* ysc   = bcw   + (size_t)BT * 4096;         // 2,097,152
    u16* Aslot_h = (u16*)(ysc + (size_t)BT * DI);     // 2,097,152 u16
    u16* Aslot_l = Aslot_h + 2097152;                 // 2,097,152
    u16* Bslot_h = Aslot_l + 2097152;                 // 8,388,608
    u16* Bslot_l = Bslot_h + 8388608;                 // 8,388,608

    dim3 blk(256);

    // splits for GEMM1: A = x (1,048,576), B = W_in (4,259,840)
    split_kernel<<<dim3(1048576 / 4 / 256), blk, 0, stream>>>(x, Aslot_h, Aslot_l, 1048576 / 4);
    split_kernel<<<dim3(4259840 / 4 / 256), blk, 0, stream>>>(W_in, Bslot_h, Bslot_l, 4259840 / 4);

    // 1) proj = x @ W_in^T : M=1024, N=4160, K=1024 (N edge guarded)
    gemm_bf16x3<64, 128, true><<<dim3(33, 16), blk, 0, stream>>>(
        Aslot_h, Aslot_l, Bslot_h, Bslot_l, proj, BT, PROJW, DM);

    // 2) conv + silu -> value (fp32 + bf16 split into A slot)
    conv_silu_kernel<<<dim3(BT * DI / 4 / 256), blk, 0, stream>>>(
        proj, dw_w, dw_b, value, Aslot_h, Aslot_l);

    // 3) dt + S precompute
    dtkd_S_kernel<<<dim3(BT * NH * NS / 256), blk, 0, stream>>>(proj, dt_bias, A_log, dt_a, S_a);

    // split B = W_bc (8,388,608)
    split_kernel<<<dim3(8388608 / 4 / 256), blk, 0, stream>>>(W_bc, Bslot_h, Bslot_l, 8388608 / 4);

    // 4) bc = value @ W_bc^T : M=1024, N=4096, K=2048
    gemm_bf16x3<64, 128, false><<<dim3(32, 16), blk, 0, stream>>>(
        Aslot_h, Aslot_l, Bslot_h, Bslot_l, bcw, BT, 4096, DI);

    // 5) normalize
    normalize_kernel<<<dim3(BT * 4096 / 256), blk, 0, stream>>>(bcw);

    // 6) scan
    scan_kernel<<<dim3(BB * NH), blk, 0, stream>>>(value, bcw, dt_a, S_a, A_log, ysc);

    // 7) fuse skip/gate -> bf16 split into A slot
    fuse_kernel<<<dim3(BT * DI / 4 / 256), blk, 0, stream>>>(
        proj, value, skip, ysc, Aslot_h, Aslot_l);

    // split B = W_out (2,097,152)
    split_kernel<<<dim3(2097152 / 4 / 256), blk, 0, stream>>>(W_out, Bslot_h, Bslot_l, 2097152 / 4);

    // 8) out = y @ W_out^T : M=1024, N=1024, K=2048
    gemm_bf16x3<64, 64, false><<<dim3(16, 16), blk, 0, stream>>>(
        Aslot_h, Aslot_l, Bslot_h, Bslot_l, out, BT, DM, DI);
}